// Round 1
// baseline (702.715 us; speedup 1.0000x reference)
//
#include <hip/hip_runtime.h>

#define N_BATCH 8
#define LQ_     2500
#define DM_     256
#define NH_     8
#define NL_     4
#define NP_     8
#define DH_     32
#define LEN_IN_ 14960

// Fixed level geometry (matches SPATIAL in the reference)
__constant__ int c_w[4]     = {176, 88, 44, 22};
__constant__ int c_h[4]     = {64, 32, 16, 8};
__constant__ int c_start[4] = {0, 11264, 14080, 14784};

// ---------------------------------------------------------------------------
// Tiled f32 GEMM: C[M,N] = A[M,K] @ B[K,N] + bias[N]
// Block 256 threads, tile 128x128, K-chunk 32, 8x8 per-thread microtile.
// A staged transposed in LDS so the compute loop reads contiguous float4s.
// ---------------------------------------------------------------------------
__global__ __launch_bounds__(256) void gemm_bias_f32(
    const float* __restrict__ A, const float* __restrict__ B,
    const float* __restrict__ bias, float* __restrict__ C,
    int M, int N, int K)
{
    const int TM = 128, TN = 128, TK = 32;
    __shared__ float As[TK][TM];   // transposed A tile
    __shared__ float Bs[TK][TN];

    int tid  = threadIdx.x;
    int ntn  = N / TN;
    int by   = blockIdx.x / ntn;
    int bx   = blockIdx.x % ntn;
    int row0 = by * TM;
    int col0 = bx * TN;
    int tr   = tid >> 4;   // 0..15
    int tc   = tid & 15;   // 0..15

    float acc[8][8];
#pragma unroll
    for (int i = 0; i < 8; ++i)
#pragma unroll
        for (int j = 0; j < 8; ++j) acc[i][j] = 0.f;

    for (int kt = 0; kt < K; kt += TK) {
        // Stage A tile (128 rows x 32 k), transposed into LDS.
#pragma unroll
        for (int i = 0; i < 4; ++i) {
            int idx = tid + i * 256;   // 0..1023
            int r   = idx >> 3;        // 0..127
            int c4  = idx & 7;         // 0..7 (float4 group)
            int row = row0 + r;
            float4 v = make_float4(0.f, 0.f, 0.f, 0.f);
            if (row < M)
                v = *(const float4*)&A[(size_t)row * K + kt + c4 * 4];
            As[c4 * 4 + 0][r] = v.x;
            As[c4 * 4 + 1][r] = v.y;
            As[c4 * 4 + 2][r] = v.z;
            As[c4 * 4 + 3][r] = v.w;
        }
        // Stage B tile (32 k x 128 cols).
#pragma unroll
        for (int i = 0; i < 4; ++i) {
            int idx = tid + i * 256;
            int kr  = idx >> 5;        // 0..31
            int c4  = idx & 31;        // 0..31
            float4 v = *(const float4*)&B[(size_t)(kt + kr) * N + col0 + c4 * 4];
            *(float4*)&Bs[kr][c4 * 4] = v;
        }
        __syncthreads();

#pragma unroll
        for (int k = 0; k < TK; ++k) {
            float4 a0 = *(const float4*)&As[k][tr * 8];
            float4 a1 = *(const float4*)&As[k][tr * 8 + 4];
            float4 b0 = *(const float4*)&Bs[k][tc * 8];
            float4 b1 = *(const float4*)&Bs[k][tc * 8 + 4];
            float a[8] = {a0.x, a0.y, a0.z, a0.w, a1.x, a1.y, a1.z, a1.w};
            float b[8] = {b0.x, b0.y, b0.z, b0.w, b1.x, b1.y, b1.z, b1.w};
#pragma unroll
            for (int i = 0; i < 8; ++i)
#pragma unroll
                for (int j = 0; j < 8; ++j)
                    acc[i][j] += a[i] * b[j];
        }
        __syncthreads();
    }

#pragma unroll
    for (int i = 0; i < 8; ++i) {
        int row = row0 + tr * 8 + i;
        if (row < M) {
#pragma unroll
            for (int j = 0; j < 8; j += 4) {
                int col = col0 + tc * 8 + j;
                float4 o;
                o.x = acc[i][j + 0] + bias[col + 0];
                o.y = acc[i][j + 1] + bias[col + 1];
                o.z = acc[i][j + 2] + bias[col + 2];
                o.w = acc[i][j + 3] + bias[col + 3];
                *(float4*)&C[(size_t)row * N + col] = o;
            }
        }
    }
}

// ---------------------------------------------------------------------------
// Per-(n,q,h): softmax over 32 logits (in place) and raw offsets -> sampling
// locations (in place):  loc = ref[z=p&3] + off / (w,h)_level
// ---------------------------------------------------------------------------
__global__ __launch_bounds__(256) void loc_softmax(
    const float* __restrict__ ref_pts,   // (n, lq, 4, 2)
    float* __restrict__ off,             // (n*lq, 256, 2) in/out
    float* __restrict__ logit)           // (n*lq, 256)    in/out
{
    int gid = blockIdx.x * 256 + threadIdx.x;
    if (gid >= N_BATCH * LQ_ * NH_) return;
    int nq = gid >> 3;
    int h  = gid & 7;

    float* lg = logit + (size_t)nq * 256 + h * 32;
    float v[32];
    float m = -1e30f;
#pragma unroll
    for (int i = 0; i < 32; ++i) { v[i] = lg[i]; m = fmaxf(m, v[i]); }
    float s = 0.f;
#pragma unroll
    for (int i = 0; i < 32; ++i) { v[i] = __expf(v[i] - m); s += v[i]; }
    float inv = 1.f / s;
#pragma unroll
    for (int i = 0; i < 32; ++i) lg[i] = v[i] * inv;

    float refs[8];
    const float* rp = ref_pts + (size_t)nq * 8;
#pragma unroll
    for (int i = 0; i < 8; ++i) refs[i] = rp[i];

    float2* op = (float2*)off + (size_t)nq * 256 + h * 32;
#pragma unroll
    for (int l = 0; l < NL_; ++l) {
        float wl = (float)c_w[l];
        float hl = (float)c_h[l];
#pragma unroll
        for (int p = 0; p < NP_; ++p) {
            int z = p & 3;
            float2 o = op[l * 8 + p];
            o.x = refs[z * 2 + 0] + o.x / wl;
            o.y = refs[z * 2 + 1] + o.y / hl;
            op[l * 8 + p] = o;
        }
    }
}

// ---------------------------------------------------------------------------
// Bilinear sampling + attention-weighted accumulation.
// One block per (n,q); 256 threads = (head = tid>>5, dh = tid&31).
// Stage: each thread computes one (h,l,p) sample's 4 corner indices and
// aw-premultiplied weights into LDS. Main loop: pure gather + FMA.
// ---------------------------------------------------------------------------
__global__ __launch_bounds__(256) void ms_sample(
    const float* __restrict__ value,   // (n, len_in, 8, 32)
    const float* __restrict__ loc,     // (n*lq, 256, 2)
    const float* __restrict__ aw,      // (n*lq, 256)
    float* __restrict__ out)           // (n, lq, 256)
{
    __shared__ int   s_idx[256][4];
    __shared__ float s_wt[256][4];

    int bid = blockIdx.x;          // n*LQ + q
    int n   = bid / LQ_;
    int tid = threadIdx.x;

    {
        int l = (tid >> 3) & 3;
        float2 lxy = ((const float2*)loc)[(size_t)bid * 256 + tid];
        float  a   = aw[(size_t)bid * 256 + tid];
        int wl = c_w[l], hl = c_h[l], st = c_start[l];
        float x = lxy.x * (float)wl - 0.5f;
        float y = lxy.y * (float)hl - 0.5f;
        float x0f = floorf(x), y0f = floorf(y);
        int   x0 = (int)x0f,  y0 = (int)y0f;
        float wx = x - x0f,   wy = y - y0f;
#pragma unroll
        for (int j = 0; j < 4; ++j) {
            int xi = x0 + (j & 1);
            int yi = y0 + (j >> 1);
            float w = ((j & 1) ? wx : 1.f - wx) * ((j >> 1) ? wy : 1.f - wy);
            bool valid = (xi >= 0) && (xi < wl) && (yi >= 0) && (yi < hl);
            int xc = min(max(xi, 0), wl - 1);
            int yc = min(max(yi, 0), hl - 1);
            s_idx[tid][j] = st + yc * wl + xc;
            s_wt[tid][j]  = valid ? a * w : 0.f;
        }
    }
    __syncthreads();

    int h  = tid >> 5;
    int dh = tid & 31;
    const float* vbase = value + (size_t)n * LEN_IN_ * DM_ + h * DH_ + dh;
    float acc = 0.f;
#pragma unroll 4
    for (int s = 0; s < 32; ++s) {
        int slot = h * 32 + s;
        int   i0 = s_idx[slot][0], i1 = s_idx[slot][1];
        int   i2 = s_idx[slot][2], i3 = s_idx[slot][3];
        float w0 = s_wt[slot][0],  w1 = s_wt[slot][1];
        float w2 = s_wt[slot][2],  w3 = s_wt[slot][3];
        acc += w0 * vbase[(size_t)i0 * DM_]
             + w1 * vbase[(size_t)i1 * DM_]
             + w2 * vbase[(size_t)i2 * DM_]
             + w3 * vbase[(size_t)i3 * DM_];
    }
    out[(size_t)bid * 256 + tid] = acc;
}

// ---------------------------------------------------------------------------
extern "C" void kernel_launch(void* const* d_in, const int* in_sizes, int n_in,
                              void* d_out, int out_size, void* d_ws, size_t ws_size,
                              hipStream_t stream)
{
    const float* query         = (const float*)d_in[0];
    // d_in[1] = query_pos: unused by the reference forward
    const float* ref_pts       = (const float*)d_in[2];
    const float* input_flatten = (const float*)d_in[3];
    const float* Wv            = (const float*)d_in[6];
    const float* bv            = (const float*)d_in[7];
    const float* Wo            = (const float*)d_in[8];
    const float* bo            = (const float*)d_in[9];
    const float* Wa            = (const float*)d_in[10];
    const float* ba            = (const float*)d_in[11];
    float* out = (float*)d_out;

    char* ws = (char*)d_ws;
    float* value = (float*)ws;                                           // 119680*256 f32
    float* off   = (float*)(ws + (size_t)119680 * 256 * 4);              // 20000*512 f32
    float* logit = (float*)(ws + (size_t)119680 * 256 * 4
                               + (size_t)20000 * 512 * 4);               // 20000*256 f32

    const int MV = N_BATCH * LEN_IN_;  // 119680
    const int MQ = N_BATCH * LQ_;      // 20000

    // value = input_flatten @ Wv + bv
    hipLaunchKernelGGL(gemm_bias_f32, dim3((MV / 128) * (256 / 128)), dim3(256), 0, stream,
                       input_flatten, Wv, bv, value, MV, 256, 256);
    // off = query @ Wo + bo
    hipLaunchKernelGGL(gemm_bias_f32, dim3(((MQ + 127) / 128) * (512 / 128)), dim3(256), 0, stream,
                       query, Wo, bo, off, MQ, 512, 256);
    // logits = query @ Wa + ba
    hipLaunchKernelGGL(gemm_bias_f32, dim3(((MQ + 127) / 128) * (256 / 128)), dim3(256), 0, stream,
                       query, Wa, ba, logit, MQ, 256, 256);
    // softmax (in place on logit) + locations (in place on off)
    hipLaunchKernelGGL(loc_softmax, dim3((MQ * NH_ + 255) / 256), dim3(256), 0, stream,
                       ref_pts, off, logit);
    // bilinear sampling + weighted sum
    hipLaunchKernelGGL(ms_sample, dim3(MQ), dim3(256), 0, stream,
                       value, off, logit, out);
}

// Round 2
// 541.023 us; speedup vs baseline: 1.2989x; 1.2989x over previous
//
#include <hip/hip_runtime.h>

#define N_BATCH 8
#define LQ_     2500
#define DM_     256
#define NH_     8
#define NL_     4
#define NP_     8
#define DH_     32
#define LEN_IN_ 14960
#define KDIM    256

// Fixed level geometry (matches SPATIAL in the reference)
__constant__ int c_w[4]     = {176, 88, 44, 22};
__constant__ int c_h[4]     = {64, 32, 16, 8};
__constant__ int c_start[4] = {0, 11264, 14080, 14784};

using bf16x8 = __attribute__((ext_vector_type(8))) short;
using f32x4  = __attribute__((ext_vector_type(4))) float;

// Truncation-based split: v ~= hi + lo with |dropped| <= 2^-16 |v|.
// hi = top 16 bits of f32 (exact to 8 mantissa bits); lo = v - hi is exact in
// f32 (residual fits the mantissa), then truncated to bf16 (error 2^-8|lo|).
static __device__ inline void split_bf16(float v, unsigned short& hi, unsigned short& lo) {
    unsigned int u = __float_as_uint(v);
    hi = (unsigned short)(u >> 16);
    float hif = __uint_as_float(u & 0xFFFF0000u);
    float l = v - hif;
    lo = (unsigned short)(__float_as_uint(l) >> 16);
}

// ---------------------------------------------------------------------------
// One-shot weight preprocessing: transpose to [N][K] (k-contiguous) and split
// into bf16 hi/lo pairs. Wo (256x512) and Wa (256x256) are concatenated into a
// single 768-column matrix so off+logits become one GEMM. bcomb = bo || ba.
// ---------------------------------------------------------------------------
__global__ __launch_bounds__(256) void conv_weights(
    const float* __restrict__ Wv, const float* __restrict__ Wo,
    const float* __restrict__ Wa, const float* __restrict__ bo,
    const float* __restrict__ ba,
    unsigned short* __restrict__ Wv_hi, unsigned short* __restrict__ Wv_lo,
    unsigned short* __restrict__ Wc_hi, unsigned short* __restrict__ Wc_lo,
    float* __restrict__ bcomb)
{
    int id = blockIdx.x * 256 + threadIdx.x;
    if (id < 256 * 256) {                       // Wv -> Wv_t[n][k]
        int n = id >> 8, k = id & 255;
        unsigned short h, l;
        split_bf16(Wv[k * 256 + n], h, l);
        Wv_hi[id] = h; Wv_lo[id] = l;
    } else {                                    // [Wo | Wa] -> Wc_t[n][k], n<768
        int id2 = id - 65536;
        if (id2 < 768 * 256) {
            int n = id2 >> 8, k = id2 & 255;
            float v = (n < 512) ? Wo[k * 512 + n] : Wa[k * 256 + (n - 512)];
            unsigned short h, l;
            split_bf16(v, h, l);
            Wc_hi[id2] = h; Wc_lo[id2] = l;
        }
    }
    if (id < 768) bcomb[id] = (id < 512) ? bo[id] : ba[id - 512];
}

// ---------------------------------------------------------------------------
// Split-precision bf16 MFMA GEMM: C[M,N] = A[M,256] @ B[256,N] + bias.
// B pre-transposed/split to [N][256] bf16 hi/lo. 128x128 tile, BK=32,
// 4 waves each owning a 64x64 quadrant (4x4 grid of 16x16x32 MFMA tiles).
// C = Ah*Bh + Ah*Bl + Al*Bh  (~f32 accuracy). LDS rows padded to 40 ushorts
// (80B) -> fragment ds_read_b128 is 2-way conflicted max (free).
// ---------------------------------------------------------------------------
__global__ __launch_bounds__(256, 2) void gemm_mfma_split(
    const float* __restrict__ A,
    const unsigned short* __restrict__ Bt_hi,
    const unsigned short* __restrict__ Bt_lo,
    const float* __restrict__ bias,
    float* __restrict__ C,
    int M, int N)
{
    __shared__ unsigned short Ah[128][40];
    __shared__ unsigned short Al[128][40];
    __shared__ unsigned short Bh[128][40];
    __shared__ unsigned short Bl[128][40];

    const int tid  = threadIdx.x;
    const int ntn  = N >> 7;
    const int by   = blockIdx.x / ntn;
    const int bx   = blockIdx.x % ntn;
    const int row0 = by << 7, col0 = bx << 7;
    const int lane = tid & 63, wave = tid >> 6;
    const int wrow = (wave & 1) << 6, wcol = (wave >> 1) << 6;
    const int r16  = lane & 15, quad = lane >> 4;

    f32x4 acc[4][4];
#pragma unroll
    for (int i = 0; i < 4; ++i)
#pragma unroll
        for (int j = 0; j < 4; ++j) acc[i][j] = (f32x4){0.f, 0.f, 0.f, 0.f};

    for (int kt = 0; kt < KDIM; kt += 32) {
        // ---- stage A (128 rows x 32 k), split f32 -> bf16 hi/lo ----
#pragma unroll
        for (int i = 0; i < 4; ++i) {
            int idx = tid + (i << 8);
            int r = idx >> 3, c4 = (idx & 7) << 2;
            int row = row0 + r;
            float4 v = make_float4(0.f, 0.f, 0.f, 0.f);
            if (row < M) v = *(const float4*)&A[(size_t)row * KDIM + kt + c4];
            ushort4 h, l;
            split_bf16(v.x, h.x, l.x);
            split_bf16(v.y, h.y, l.y);
            split_bf16(v.z, h.z, l.z);
            split_bf16(v.w, h.w, l.w);
            *(ushort4*)&Ah[r][c4] = h;
            *(ushort4*)&Al[r][c4] = l;
        }
        // ---- stage B (128 cols x 32 k), straight 16B copies ----
#pragma unroll
        for (int i = 0; i < 2; ++i) {
            int idx = tid + (i << 8);
            int n = idx >> 2, g = (idx & 3) << 3;
            size_t goff = (size_t)(col0 + n) * KDIM + kt + g;
            *(uint4*)&Bh[n][g] = *(const uint4*)&Bt_hi[goff];
            *(uint4*)&Bl[n][g] = *(const uint4*)&Bt_lo[goff];
        }
        __syncthreads();

        // ---- fragments + MFMA ----
        bf16x8 bh[4], bl[4];
#pragma unroll
        for (int tn = 0; tn < 4; ++tn) {
            int n = wcol + tn * 16 + r16;
            bh[tn] = *(const bf16x8*)&Bh[n][quad << 3];
            bl[tn] = *(const bf16x8*)&Bl[n][quad << 3];
        }
#pragma unroll
        for (int tm = 0; tm < 4; ++tm) {
            int m = wrow + tm * 16 + r16;
            bf16x8 ah = *(const bf16x8*)&Ah[m][quad << 3];
            bf16x8 al = *(const bf16x8*)&Al[m][quad << 3];
#pragma unroll
            for (int tn = 0; tn < 4; ++tn) {
                acc[tm][tn] = __builtin_amdgcn_mfma_f32_16x16x32_bf16(al, bh[tn], acc[tm][tn], 0, 0, 0);
                acc[tm][tn] = __builtin_amdgcn_mfma_f32_16x16x32_bf16(ah, bl[tn], acc[tm][tn], 0, 0, 0);
                acc[tm][tn] = __builtin_amdgcn_mfma_f32_16x16x32_bf16(ah, bh[tn], acc[tm][tn], 0, 0, 0);
            }
        }
        __syncthreads();
    }

    // ---- epilogue: C/D layout col=lane&15, row=quad*4+reg (m89/m91) ----
    float bvs[4];
#pragma unroll
    for (int tn = 0; tn < 4; ++tn) bvs[tn] = bias[col0 + wcol + tn * 16 + r16];
#pragma unroll
    for (int tm = 0; tm < 4; ++tm) {
#pragma unroll
        for (int i = 0; i < 4; ++i) {
            int row = row0 + wrow + tm * 16 + (quad << 2) + i;
            if (row < M) {
                float* crow = C + (size_t)row * N + col0 + wcol + r16;
#pragma unroll
                for (int tn = 0; tn < 4; ++tn)
                    crow[tn * 16] = acc[tm][tn][i] + bvs[tn];
            }
        }
    }
}

// ---------------------------------------------------------------------------
// Per-(n,q,h): softmax over 32 logits and offsets -> sampling locations,
// both in place on the combined (n*lq, 768) buffer: [0,512)=off, [512,768)=logit.
// ---------------------------------------------------------------------------
__global__ __launch_bounds__(256) void loc_softmax(
    const float* __restrict__ ref_pts,   // (n, lq, 4, 2)
    float* __restrict__ comb)            // (n*lq, 768) in/out
{
    int gid = blockIdx.x * 256 + threadIdx.x;
    if (gid >= N_BATCH * LQ_ * NH_) return;
    int nq = gid >> 3;
    int h  = gid & 7;

    float* base = comb + (size_t)nq * 768;
    float* lg = base + 512 + h * 32;
    float v[32];
    float m = -1e30f;
#pragma unroll
    for (int i = 0; i < 32; ++i) { v[i] = lg[i]; m = fmaxf(m, v[i]); }
    float s = 0.f;
#pragma unroll
    for (int i = 0; i < 32; ++i) { v[i] = __expf(v[i] - m); s += v[i]; }
    float inv = 1.f / s;
#pragma unroll
    for (int i = 0; i < 32; ++i) lg[i] = v[i] * inv;

    float refs[8];
    const float* rp = ref_pts + (size_t)nq * 8;
#pragma unroll
    for (int i = 0; i < 8; ++i) refs[i] = rp[i];

    float2* op = (float2*)base + h * 32;
#pragma unroll
    for (int l = 0; l < NL_; ++l) {
        float wl = (float)c_w[l];
        float hl = (float)c_h[l];
#pragma unroll
        for (int p = 0; p < NP_; ++p) {
            int z = p & 3;
            float2 o = op[l * 8 + p];
            o.x = refs[z * 2 + 0] + o.x / wl;
            o.y = refs[z * 2 + 1] + o.y / hl;
            op[l * 8 + p] = o;
        }
    }
}

// ---------------------------------------------------------------------------
// Bilinear sampling + attention-weighted accumulation.
// One block per (n,q); 256 threads = (head = tid>>5, dh = tid&31).
// ---------------------------------------------------------------------------
__global__ __launch_bounds__(256) void ms_sample(
    const float* __restrict__ value,   // (n, len_in, 8, 32)
    const float* __restrict__ comb,    // (n*lq, 768): loc pairs + aw
    float* __restrict__ out)           // (n, lq, 256)
{
    __shared__ int   s_idx[256][4];
    __shared__ float s_wt[256][4];

    int bid = blockIdx.x;          // n*LQ + q
    int n   = bid / LQ_;
    int tid = threadIdx.x;
    const float* base = comb + (size_t)bid * 768;

    {
        int l = (tid >> 3) & 3;
        float2 lxy = ((const float2*)base)[tid];
        float  a   = base[512 + tid];
        int wl = c_w[l], hl = c_h[l], st = c_start[l];
        float x = lxy.x * (float)wl - 0.5f;
        float y = lxy.y * (float)hl - 0.5f;
        float x0f = floorf(x), y0f = floorf(y);
        int   x0 = (int)x0f,  y0 = (int)y0f;
        float wx = x - x0f,   wy = y - y0f;
#pragma unroll
        for (int j = 0; j < 4; ++j) {
            int xi = x0 + (j & 1);
            int yi = y0 + (j >> 1);
            float w = ((j & 1) ? wx : 1.f - wx) * ((j >> 1) ? wy : 1.f - wy);
            bool valid = (xi >= 0) && (xi < wl) && (yi >= 0) && (yi < hl);
            int xc = min(max(xi, 0), wl - 1);
            int yc = min(max(yi, 0), hl - 1);
            s_idx[tid][j] = st + yc * wl + xc;
            s_wt[tid][j]  = valid ? a * w : 0.f;
        }
    }
    __syncthreads();

    int h  = tid >> 5;
    int dh = tid & 31;
    const float* vbase = value + (size_t)n * LEN_IN_ * DM_ + h * DH_ + dh;
    float acc = 0.f;
#pragma unroll 4
    for (int s = 0; s < 32; ++s) {
        int slot = h * 32 + s;
        int   i0 = s_idx[slot][0], i1 = s_idx[slot][1];
        int   i2 = s_idx[slot][2], i3 = s_idx[slot][3];
        float w0 = s_wt[slot][0],  w1 = s_wt[slot][1];
        float w2 = s_wt[slot][2],  w3 = s_wt[slot][3];
        acc += w0 * vbase[(size_t)i0 * DM_]
             + w1 * vbase[(size_t)i1 * DM_]
             + w2 * vbase[(size_t)i2 * DM_]
             + w3 * vbase[(size_t)i3 * DM_];
    }
    out[(size_t)bid * 256 + tid] = acc;
}

// ---------------------------------------------------------------------------
extern "C" void kernel_launch(void* const* d_in, const int* in_sizes, int n_in,
                              void* d_out, int out_size, void* d_ws, size_t ws_size,
                              hipStream_t stream)
{
    const float* query         = (const float*)d_in[0];
    const float* ref_pts       = (const float*)d_in[2];
    const float* input_flatten = (const float*)d_in[3];
    const float* Wv            = (const float*)d_in[6];
    const float* bv            = (const float*)d_in[7];
    const float* Wo            = (const float*)d_in[8];
    const float* bo            = (const float*)d_in[9];
    const float* Wa            = (const float*)d_in[10];
    const float* ba            = (const float*)d_in[11];
    float* out = (float*)d_out;

    char* ws = (char*)d_ws;
    size_t o = 0;
    unsigned short* Wv_hi = (unsigned short*)(ws + o); o += 256 * 256 * 2;
    unsigned short* Wv_lo = (unsigned short*)(ws + o); o += 256 * 256 * 2;
    unsigned short* Wc_hi = (unsigned short*)(ws + o); o += 768 * 256 * 2;
    unsigned short* Wc_lo = (unsigned short*)(ws + o); o += 768 * 256 * 2;
    float*          bcomb = (float*)(ws + o);          o += 768 * 4;
    o = (o + 511) & ~(size_t)511;
    float* value = (float*)(ws + o); o += (size_t)119680 * 256 * 4;
    float* combq = (float*)(ws + o); o += (size_t)20000 * 768 * 4;

    const int MV = N_BATCH * LEN_IN_;  // 119680
    const int MQ = N_BATCH * LQ_;      // 20000

    // Weight transpose/split (tiny, once per launch)
    hipLaunchKernelGGL(conv_weights, dim3(1024), dim3(256), 0, stream,
                       Wv, Wo, Wa, bo, ba, Wv_hi, Wv_lo, Wc_hi, Wc_lo, bcomb);
    // value = input_flatten @ Wv + bv
    hipLaunchKernelGGL(gemm_mfma_split, dim3((MV / 128) * 2), dim3(256), 0, stream,
                       input_flatten, Wv_hi, Wv_lo, bv, value, MV, 256);
    // [off | logits] = query @ [Wo | Wa] + [bo | ba]
    hipLaunchKernelGGL(gemm_mfma_split, dim3(((MQ + 127) / 128) * 6), dim3(256), 0, stream,
                       query, Wc_hi, Wc_lo, bcomb, combq, MQ, 768);
    // softmax + locations (in place on combq)
    hipLaunchKernelGGL(loc_softmax, dim3((MQ * NH_ + 255) / 256), dim3(256), 0, stream,
                       ref_pts, combq);
    // bilinear sampling + weighted sum
    hipLaunchKernelGGL(ms_sample, dim3(MQ), dim3(256), 0, stream,
                       value, combq, out);
}

// Round 3
// 448.978 us; speedup vs baseline: 1.5651x; 1.2050x over previous
//
#include <hip/hip_runtime.h>
#include <hip/hip_fp16.h>

#define N_BATCH 8
#define LQ_     2500
#define DM_     256
#define NH_     8
#define NL_     4
#define NP_     8
#define DH_     32
#define LEN_IN_ 14960
#define KDIM    256

// Fixed level geometry (matches SPATIAL in the reference)
__constant__ int c_w[4]     = {176, 88, 44, 22};
__constant__ int c_h[4]     = {64, 32, 16, 8};
__constant__ int c_start[4] = {0, 11264, 14080, 14784};

using bf16x8 = __attribute__((ext_vector_type(8))) short;
using f32x4  = __attribute__((ext_vector_type(4))) float;

// Truncation-based split: v ~= hi + lo with |dropped| <= 2^-16 |v|.
static __device__ inline void split_bf16(float v, unsigned short& hi, unsigned short& lo) {
    unsigned int u = __float_as_uint(v);
    hi = (unsigned short)(u >> 16);
    float hif = __uint_as_float(u & 0xFFFF0000u);
    float l = v - hif;
    lo = (unsigned short)(__float_as_uint(l) >> 16);
}

// round-to-nearest-even f32 -> bf16
static __device__ inline unsigned short f2bf_rne(float v) {
    unsigned int u = __float_as_uint(v);
    u += 0x7FFFu + ((u >> 16) & 1u);
    return (unsigned short)(u >> 16);
}

// ---------------------------------------------------------------------------
// One-shot weight preprocessing: transpose to [N][K] (k-contiguous) and split
// into bf16 hi/lo pairs. Wo (256x512) and Wa (256x256) concatenated -> 768 cols.
// ---------------------------------------------------------------------------
__global__ __launch_bounds__(256) void conv_weights(
    const float* __restrict__ Wv, const float* __restrict__ Wo,
    const float* __restrict__ Wa, const float* __restrict__ bo,
    const float* __restrict__ ba,
    unsigned short* __restrict__ Wv_hi, unsigned short* __restrict__ Wv_lo,
    unsigned short* __restrict__ Wc_hi, unsigned short* __restrict__ Wc_lo,
    float* __restrict__ bcomb)
{
    int id = blockIdx.x * 256 + threadIdx.x;
    if (id < 256 * 256) {                       // Wv -> Wv_t[n][k]
        int n = id >> 8, k = id & 255;
        unsigned short h, l;
        split_bf16(Wv[k * 256 + n], h, l);
        Wv_hi[id] = h; Wv_lo[id] = l;
    } else {                                    // [Wo | Wa] -> Wc_t[n][k]
        int id2 = id - 65536;
        if (id2 < 768 * 256) {
            int n = id2 >> 8, k = id2 & 255;
            float v = (n < 512) ? Wo[k * 512 + n] : Wa[k * 256 + (n - 512)];
            unsigned short h, l;
            split_bf16(v, h, l);
            Wc_hi[id2] = h; Wc_lo[id2] = l;
        }
    }
    if (id < 768) bcomb[id] = (id < 512) ? bo[id] : ba[id - 512];
}

// ---------------------------------------------------------------------------
// Split-precision bf16 MFMA GEMM: C[M,N] = A[M,256] @ B[256,N] + bias.
// BF16_OUT=false: f32 row-major C.
// BF16_OUT=true : bf16 C scattered into value layout (n, head, pixel, dh)
//                 (row = n*LEN_IN+pixel, col = head*32+dh), fixed geometry.
// ---------------------------------------------------------------------------
template <bool BF16_OUT>
__global__ __launch_bounds__(256, 2) void gemm_mfma_split(
    const float* __restrict__ A,
    const unsigned short* __restrict__ Bt_hi,
    const unsigned short* __restrict__ Bt_lo,
    const float* __restrict__ bias,
    float* __restrict__ C,
    unsigned short* __restrict__ Cb,
    int M, int N)
{
    __shared__ unsigned short Ah[128][40];
    __shared__ unsigned short Al[128][40];
    __shared__ unsigned short Bh[128][40];
    __shared__ unsigned short Bl[128][40];

    const int tid  = threadIdx.x;
    const int ntn  = N >> 7;
    const int by   = blockIdx.x / ntn;
    const int bx   = blockIdx.x % ntn;
    const int row0 = by << 7, col0 = bx << 7;
    const int lane = tid & 63, wave = tid >> 6;
    const int wrow = (wave & 1) << 6, wcol = (wave >> 1) << 6;
    const int r16  = lane & 15, quad = lane >> 4;

    f32x4 acc[4][4];
#pragma unroll
    for (int i = 0; i < 4; ++i)
#pragma unroll
        for (int j = 0; j < 4; ++j) acc[i][j] = (f32x4){0.f, 0.f, 0.f, 0.f};

    for (int kt = 0; kt < KDIM; kt += 32) {
#pragma unroll
        for (int i = 0; i < 4; ++i) {
            int idx = tid + (i << 8);
            int r = idx >> 3, c4 = (idx & 7) << 2;
            int row = row0 + r;
            float4 v = make_float4(0.f, 0.f, 0.f, 0.f);
            if (row < M) v = *(const float4*)&A[(size_t)row * KDIM + kt + c4];
            ushort4 h, l;
            split_bf16(v.x, h.x, l.x);
            split_bf16(v.y, h.y, l.y);
            split_bf16(v.z, h.z, l.z);
            split_bf16(v.w, h.w, l.w);
            *(ushort4*)&Ah[r][c4] = h;
            *(ushort4*)&Al[r][c4] = l;
        }
#pragma unroll
        for (int i = 0; i < 2; ++i) {
            int idx = tid + (i << 8);
            int n = idx >> 2, g = (idx & 3) << 3;
            size_t goff = (size_t)(col0 + n) * KDIM + kt + g;
            *(uint4*)&Bh[n][g] = *(const uint4*)&Bt_hi[goff];
            *(uint4*)&Bl[n][g] = *(const uint4*)&Bt_lo[goff];
        }
        __syncthreads();

        bf16x8 bh[4], bl[4];
#pragma unroll
        for (int tn = 0; tn < 4; ++tn) {
            int n = wcol + tn * 16 + r16;
            bh[tn] = *(const bf16x8*)&Bh[n][quad << 3];
            bl[tn] = *(const bf16x8*)&Bl[n][quad << 3];
        }
#pragma unroll
        for (int tm = 0; tm < 4; ++tm) {
            int m = wrow + tm * 16 + r16;
            bf16x8 ah = *(const bf16x8*)&Ah[m][quad << 3];
            bf16x8 al = *(const bf16x8*)&Al[m][quad << 3];
#pragma unroll
            for (int tn = 0; tn < 4; ++tn) {
                acc[tm][tn] = __builtin_amdgcn_mfma_f32_16x16x32_bf16(al, bh[tn], acc[tm][tn], 0, 0, 0);
                acc[tm][tn] = __builtin_amdgcn_mfma_f32_16x16x32_bf16(ah, bl[tn], acc[tm][tn], 0, 0, 0);
                acc[tm][tn] = __builtin_amdgcn_mfma_f32_16x16x32_bf16(ah, bh[tn], acc[tm][tn], 0, 0, 0);
            }
        }
        __syncthreads();
    }

    // epilogue: C/D layout col=lane&15, row=quad*4+reg
    float bvs[4];
#pragma unroll
    for (int tn = 0; tn < 4; ++tn) bvs[tn] = bias[col0 + wcol + tn * 16 + r16];
#pragma unroll
    for (int tm = 0; tm < 4; ++tm) {
#pragma unroll
        for (int i = 0; i < 4; ++i) {
            int row = row0 + wrow + tm * 16 + (quad << 2) + i;
            if (row < M) {
                if (!BF16_OUT) {
                    float* crow = C + (size_t)row * N + col0 + wcol + r16;
#pragma unroll
                    for (int tn = 0; tn < 4; ++tn)
                        crow[tn * 16] = acc[tm][tn][i] + bvs[tn];
                } else {
                    int n   = row / LEN_IN_;
                    int pix = row - n * LEN_IN_;
#pragma unroll
                    for (int tn = 0; tn < 4; ++tn) {
                        int col = col0 + wcol + tn * 16 + r16;
                        int h = col >> 5, dh = col & 31;
                        size_t addr = ((size_t)(n * NH_ + h) * LEN_IN_ + pix) * DH_ + dh;
                        Cb[addr] = f2bf_rne(acc[tm][tn][i] + bvs[tn]);
                    }
                }
            }
        }
    }
}

// ---------------------------------------------------------------------------
// Fused softmax + location + bilinear sampling + weighted accumulation.
// One block per 8 queries. Stage: 256 threads = (q=tid>>5, h=(tid>>2)&7,
// l=tid&3), each handles 8 points: softmax across l via shfl_xor, builds a
// 16B descriptor per sample (ushort4 corner idx + half4 aw-premult weights).
// Gather: 256 threads = (q, h, dhg=tid&3), bf16x8 (16B) corner loads.
// ---------------------------------------------------------------------------
__global__ __launch_bounds__(256) void ms_sample(
    const unsigned short* __restrict__ value,  // (n, 8, len_in, 32) bf16
    const float* __restrict__ comb,            // (n*lq, 768): off(512) | logit(256)
    const float* __restrict__ ref_pts,         // (n*lq, 4, 2)
    float* __restrict__ out)                   // (n*lq, 256)
{
    __shared__ uint4 s_desc[2048];             // [q][h][32]

    const int bid = blockIdx.x;
    const int tid = threadIdx.x;

    { // ---- stage ----
        int q = tid >> 5, h = (tid >> 2) & 7, l = tid & 3;
        int nq = bid * 8 + q;
        const float* row = comb + (size_t)nq * 768;

        float4 L0 = *(const float4*)&row[512 + h * 32 + l * 8];
        float4 L1 = *(const float4*)&row[512 + h * 32 + l * 8 + 4];
        float lg[8] = {L0.x, L0.y, L0.z, L0.w, L1.x, L1.y, L1.z, L1.w};
        float m = lg[0];
#pragma unroll
        for (int i = 1; i < 8; ++i) m = fmaxf(m, lg[i]);
        m = fmaxf(m, __shfl_xor(m, 1));
        m = fmaxf(m, __shfl_xor(m, 2));
        float e[8], s = 0.f;
#pragma unroll
        for (int i = 0; i < 8; ++i) { e[i] = __expf(lg[i] - m); s += e[i]; }
        s += __shfl_xor(s, 1);
        s += __shfl_xor(s, 2);
        float inv = 1.f / s;

        float4 R0 = *(const float4*)&ref_pts[(size_t)nq * 8];
        float4 R1 = *(const float4*)&ref_pts[(size_t)nq * 8 + 4];
        float rx[4] = {R0.x, R0.z, R1.x, R1.z};
        float ry[4] = {R0.y, R0.w, R1.y, R1.w};

        float off[16];
#pragma unroll
        for (int i = 0; i < 4; ++i)
            *(float4*)&off[i * 4] = *(const float4*)&row[h * 64 + l * 16 + i * 4];

        float wl = (float)c_w[l], hl = (float)c_h[l];
        int wli = c_w[l], hli = c_h[l], st = c_start[l];
        uint4* dst = &s_desc[((q * 8 + h) * 4 + l) * 8];
#pragma unroll
        for (int p = 0; p < 8; ++p) {
            int z = p & 3;
            float a = e[p] * inv;
            float x = rx[z] * wl + off[p * 2 + 0] - 0.5f;
            float y = ry[z] * hl + off[p * 2 + 1] - 0.5f;
            float x0f = floorf(x), y0f = floorf(y);
            int   x0 = (int)x0f,  y0 = (int)y0f;
            float wx = x - x0f,   wy = y - y0f;
            unsigned short ix[4];
            float wt[4];
#pragma unroll
            for (int j = 0; j < 4; ++j) {
                int xi = x0 + (j & 1);
                int yi = y0 + (j >> 1);
                float w = ((j & 1) ? wx : 1.f - wx) * ((j >> 1) ? wy : 1.f - wy);
                bool valid = (xi >= 0) && (xi < wli) && (yi >= 0) && (yi < hli);
                int xc = min(max(xi, 0), wli - 1);
                int yc = min(max(yi, 0), hli - 1);
                ix[j] = (unsigned short)(st + yc * wli + xc);
                wt[j] = valid ? a * w : 0.f;
            }
            uint4 d;
            d.x = (unsigned int)ix[0] | ((unsigned int)ix[1] << 16);
            d.y = (unsigned int)ix[2] | ((unsigned int)ix[3] << 16);
            __half2 h01 = __floats2half2_rn(wt[0], wt[1]);
            __half2 h23 = __floats2half2_rn(wt[2], wt[3]);
            d.z = *(unsigned int*)&h01;
            d.w = *(unsigned int*)&h23;
            dst[p] = d;
        }
    }
    __syncthreads();

    // ---- gather ----
    int q = tid >> 5, h = (tid >> 2) & 7, dhg = tid & 3;
    int nq = bid * 8 + q;
    int n  = nq / LQ_;
    const unsigned short* vb = value
        + ((size_t)(n * NH_ + h) * LEN_IN_) * DH_ + dhg * 8;
    const uint4* desc = &s_desc[(q * 8 + h) * 32];

    float acc[8];
#pragma unroll
    for (int i = 0; i < 8; ++i) acc[i] = 0.f;

#pragma unroll 2
    for (int s = 0; s < 32; ++s) {
        uint4 d = desc[s];
        float2 w01 = __half22float2(*(const __half2*)&d.z);
        float2 w23 = __half22float2(*(const __half2*)&d.w);
        int i0 = d.x & 0xFFFF, i1 = d.x >> 16;
        int i2 = d.y & 0xFFFF, i3 = d.y >> 16;
        uint4 v0 = *(const uint4*)(vb + i0 * DH_);
        uint4 v1 = *(const uint4*)(vb + i1 * DH_);
        uint4 v2 = *(const uint4*)(vb + i2 * DH_);
        uint4 v3 = *(const uint4*)(vb + i3 * DH_);
        const uint4* vv[4] = {&v0, &v1, &v2, &v3};
        float ww[4] = {w01.x, w01.y, w23.x, w23.y};
#pragma unroll
        for (int c = 0; c < 4; ++c) {
            uint4 v = *vv[c];
            float w = ww[c];
            acc[0] = fmaf(__uint_as_float(v.x << 16), w, acc[0]);
            acc[1] = fmaf(__uint_as_float(v.x & 0xFFFF0000u), w, acc[1]);
            acc[2] = fmaf(__uint_as_float(v.y << 16), w, acc[2]);
            acc[3] = fmaf(__uint_as_float(v.y & 0xFFFF0000u), w, acc[3]);
            acc[4] = fmaf(__uint_as_float(v.z << 16), w, acc[4]);
            acc[5] = fmaf(__uint_as_float(v.z & 0xFFFF0000u), w, acc[5]);
            acc[6] = fmaf(__uint_as_float(v.w << 16), w, acc[6]);
            acc[7] = fmaf(__uint_as_float(v.w & 0xFFFF0000u), w, acc[7]);
        }
    }

    float* op = out + (size_t)nq * 256 + h * 32 + dhg * 8;
    *(float4*)&op[0] = make_float4(acc[0], acc[1], acc[2], acc[3]);
    *(float4*)&op[4] = make_float4(acc[4], acc[5], acc[6], acc[7]);
}

// ---------------------------------------------------------------------------
extern "C" void kernel_launch(void* const* d_in, const int* in_sizes, int n_in,
                              void* d_out, int out_size, void* d_ws, size_t ws_size,
                              hipStream_t stream)
{
    const float* query         = (const float*)d_in[0];
    const float* ref_pts       = (const float*)d_in[2];
    const float* input_flatten = (const float*)d_in[3];
    const float* Wv            = (const float*)d_in[6];
    const float* bv            = (const float*)d_in[7];
    const float* Wo            = (const float*)d_in[8];
    const float* bo            = (const float*)d_in[9];
    const float* Wa            = (const float*)d_in[10];
    const float* ba            = (const float*)d_in[11];
    float* out = (float*)d_out;

    char* ws = (char*)d_ws;
    size_t o = 0;
    unsigned short* Wv_hi = (unsigned short*)(ws + o); o += 256 * 256 * 2;
    unsigned short* Wv_lo = (unsigned short*)(ws + o); o += 256 * 256 * 2;
    unsigned short* Wc_hi = (unsigned short*)(ws + o); o += 768 * 256 * 2;
    unsigned short* Wc_lo = (unsigned short*)(ws + o); o += 768 * 256 * 2;
    float*          bcomb = (float*)(ws + o);          o += 768 * 4;
    o = (o + 511) & ~(size_t)511;
    unsigned short* value = (unsigned short*)(ws + o); o += (size_t)119680 * 256 * 2;
    o = (o + 511) & ~(size_t)511;
    float* combq = (float*)(ws + o); o += (size_t)20000 * 768 * 4;

    const int MV = N_BATCH * LEN_IN_;  // 119680
    const int MQ = N_BATCH * LQ_;      // 20000

    hipLaunchKernelGGL(conv_weights, dim3(1024), dim3(256), 0, stream,
                       Wv, Wo, Wa, bo, ba, Wv_hi, Wv_lo, Wc_hi, Wc_lo, bcomb);
    // value (bf16, (n,h,pix,dh) layout) = input_flatten @ Wv + bv
    hipLaunchKernelGGL((gemm_mfma_split<true>), dim3((MV / 128) * 2), dim3(256), 0, stream,
                       input_flatten, Wv_hi, Wv_lo, bv, (float*)nullptr, value, MV, 256);
    // [off | logits] = query @ [Wo | Wa] + [bo | ba]   (f32)
    hipLaunchKernelGGL((gemm_mfma_split<false>), dim3(((MQ + 127) / 128) * 6), dim3(256), 0, stream,
                       query, Wc_hi, Wc_lo, bcomb, combq, (unsigned short*)nullptr, MQ, 768);
    // fused softmax + loc + bilinear sample + weighted sum
    hipLaunchKernelGGL(ms_sample, dim3(MQ / 8), dim3(256), 0, stream,
                       value, combq, ref_pts, out);
}

// Round 4
// 402.565 us; speedup vs baseline: 1.7456x; 1.1153x over previous
//
#include <hip/hip_runtime.h>
#include <hip/hip_fp16.h>

#define N_BATCH 8
#define LQ_     2500
#define DM_     256
#define NH_     8
#define NL_     4
#define NP_     8
#define DH_     32
#define LEN_IN_ 14960
#define KDIM    256

// Fixed level geometry (matches SPATIAL in the reference)
__constant__ int c_w[4]     = {176, 88, 44, 22};
__constant__ int c_h[4]     = {64, 32, 16, 8};
__constant__ int c_start[4] = {0, 11264, 14080, 14784};

using bf16x8 = __attribute__((ext_vector_type(8))) short;
using f32x4  = __attribute__((ext_vector_type(4))) float;

// Truncation-based split: v ~= hi + lo with |dropped| <= 2^-16 |v|.
static __device__ inline void split_bf16(float v, unsigned short& hi, unsigned short& lo) {
    unsigned int u = __float_as_uint(v);
    hi = (unsigned short)(u >> 16);
    float hif = __uint_as_float(u & 0xFFFF0000u);
    float l = v - hif;
    lo = (unsigned short)(__float_as_uint(l) >> 16);
}

// round-to-nearest-even f32 -> bf16
static __device__ inline unsigned short f2bf_rne(float v) {
    unsigned int u = __float_as_uint(v);
    u += 0x7FFFu + ((u >> 16) & 1u);
    return (unsigned short)(u >> 16);
}

// ---------------------------------------------------------------------------
// One-shot weight preprocessing: transpose to [N][K] (k-contiguous) and split
// into bf16 hi/lo pairs. Wo (256x512) and Wa (256x256) concatenated -> 768 cols.
// ---------------------------------------------------------------------------
__global__ __launch_bounds__(256) void conv_weights(
    const float* __restrict__ Wv, const float* __restrict__ Wo,
    const float* __restrict__ Wa, const float* __restrict__ bo,
    const float* __restrict__ ba,
    unsigned short* __restrict__ Wv_hi, unsigned short* __restrict__ Wv_lo,
    unsigned short* __restrict__ Wc_hi, unsigned short* __restrict__ Wc_lo,
    float* __restrict__ bcomb)
{
    int id = blockIdx.x * 256 + threadIdx.x;
    if (id < 256 * 256) {                       // Wv -> Wv_t[n][k]
        int n = id >> 8, k = id & 255;
        unsigned short h, l;
        split_bf16(Wv[k * 256 + n], h, l);
        Wv_hi[id] = h; Wv_lo[id] = l;
    } else {                                    // [Wo | Wa] -> Wc_t[n][k]
        int id2 = id - 65536;
        if (id2 < 768 * 256) {
            int n = id2 >> 8, k = id2 & 255;
            float v = (n < 512) ? Wo[k * 512 + n] : Wa[k * 256 + (n - 512)];
            unsigned short h, l;
            split_bf16(v, h, l);
            Wc_hi[id2] = h; Wc_lo[id2] = l;
        }
    }
    if (id < 768) bcomb[id] = (id < 512) ? bo[id] : ba[id - 512];
}

// ---------------------------------------------------------------------------
// 2-term split MFMA GEMM: C = A @ B + bias, A RNE-rounded to single bf16
// in-kernel, B pre-split hi/lo (C = Ah*Bh + Ah*Bl; error ~= 2^-9 * rowNorm).
// Block = 512 threads (8 waves), tile 128x128, BK=32; wave owns 64x32
// (4x2 grid of 16x16x32 tiles, 32 AGPRs). Register-prefetch pipeline:
// global loads for iter k+1 are issued right after the first barrier so they
// overlap fragment reads + MFMA + the second barrier. launch_bounds(512,4)
// caps regs at 128 -> 4 waves/SIMD = 2 blocks/CU.
// BF16_OUT=true scatters bf16 C into value layout (n, head, pixel, dh).
// ---------------------------------------------------------------------------
template <bool BF16_OUT>
__global__ __launch_bounds__(512, 4) void gemm_mfma2(
    const float* __restrict__ A,
    const unsigned short* __restrict__ Bt_hi,
    const unsigned short* __restrict__ Bt_lo,
    const float* __restrict__ bias,
    float* __restrict__ C,
    unsigned short* __restrict__ Cb,
    int M, int N)
{
    __shared__ unsigned short As[128][40];
    __shared__ unsigned short Bh[128][40];
    __shared__ unsigned short Bl[128][40];

    const int tid  = threadIdx.x;
    const int ntn  = N >> 7;
    const int by   = blockIdx.x / ntn;
    const int bx   = blockIdx.x % ntn;
    const int row0 = by << 7, col0 = bx << 7;
    const int lane = tid & 63, wave = tid >> 6;
    const int wrow = (wave & 1) << 6, wcol = (wave >> 1) << 5;
    const int r16  = lane & 15, quad = lane >> 4;

    // staging indices
    const int ar0 = tid >> 3;            // A row (i-stride 64): 0..63
    const int ac4 = (tid & 7) << 2;      // A k-offset (float4 group)
    const int bn  = tid >> 2;            // B row (col): 0..127
    const int bg  = (tid & 3) << 3;      // B k-offset (uint4 group)

    float4 pa[2];
    uint4  pbh, pbl;

    // prologue: issue loads for kt=0
#pragma unroll
    for (int i = 0; i < 2; ++i) {
        int row = row0 + ar0 + (i << 6);
        pa[i] = (row < M) ? *(const float4*)&A[(size_t)row * KDIM + ac4]
                          : make_float4(0.f, 0.f, 0.f, 0.f);
    }
    {
        size_t goff = (size_t)(col0 + bn) * KDIM + bg;
        pbh = *(const uint4*)&Bt_hi[goff];
        pbl = *(const uint4*)&Bt_lo[goff];
    }

    f32x4 acc[4][2];
#pragma unroll
    for (int i = 0; i < 4; ++i)
#pragma unroll
        for (int j = 0; j < 2; ++j) acc[i][j] = (f32x4){0.f, 0.f, 0.f, 0.f};

#pragma unroll
    for (int kt = 0; kt < KDIM; kt += 32) {
        // ---- store prefetched tile to LDS ----
#pragma unroll
        for (int i = 0; i < 2; ++i) {
            int r = ar0 + (i << 6);
            ushort4 hv;
            hv.x = f2bf_rne(pa[i].x);
            hv.y = f2bf_rne(pa[i].y);
            hv.z = f2bf_rne(pa[i].z);
            hv.w = f2bf_rne(pa[i].w);
            *(ushort4*)&As[r][ac4] = hv;
        }
        *(uint4*)&Bh[bn][bg] = pbh;
        *(uint4*)&Bl[bn][bg] = pbl;
        __syncthreads();

        // ---- issue next tile's loads (overlap with fragments + MFMA) ----
        if (kt + 32 < KDIM) {
#pragma unroll
            for (int i = 0; i < 2; ++i) {
                int row = row0 + ar0 + (i << 6);
                pa[i] = (row < M)
                    ? *(const float4*)&A[(size_t)row * KDIM + kt + 32 + ac4]
                    : make_float4(0.f, 0.f, 0.f, 0.f);
            }
            size_t goff = (size_t)(col0 + bn) * KDIM + kt + 32 + bg;
            pbh = *(const uint4*)&Bt_hi[goff];
            pbl = *(const uint4*)&Bt_lo[goff];
        }

        // ---- fragments + MFMA ----
        bf16x8 fbh[2], fbl[2], fa[4];
#pragma unroll
        for (int tn = 0; tn < 2; ++tn) {
            int n = wcol + tn * 16 + r16;
            fbh[tn] = *(const bf16x8*)&Bh[n][quad << 3];
            fbl[tn] = *(const bf16x8*)&Bl[n][quad << 3];
        }
#pragma unroll
        for (int tm = 0; tm < 4; ++tm)
            fa[tm] = *(const bf16x8*)&As[wrow + tm * 16 + r16][quad << 3];
#pragma unroll
        for (int tm = 0; tm < 4; ++tm)
#pragma unroll
            for (int tn = 0; tn < 2; ++tn) {
                acc[tm][tn] = __builtin_amdgcn_mfma_f32_16x16x32_bf16(fa[tm], fbl[tn], acc[tm][tn], 0, 0, 0);
                acc[tm][tn] = __builtin_amdgcn_mfma_f32_16x16x32_bf16(fa[tm], fbh[tn], acc[tm][tn], 0, 0, 0);
            }
        __syncthreads();
    }

    // ---- epilogue: C/D layout col=lane&15, row=quad*4+reg ----
    float bvs[2];
#pragma unroll
    for (int tn = 0; tn < 2; ++tn) bvs[tn] = bias[col0 + wcol + tn * 16 + r16];
#pragma unroll
    for (int tm = 0; tm < 4; ++tm) {
#pragma unroll
        for (int i = 0; i < 4; ++i) {
            int row = row0 + wrow + tm * 16 + (quad << 2) + i;
            if (row < M) {
                if (!BF16_OUT) {
                    float* crow = C + (size_t)row * N + col0 + wcol + r16;
#pragma unroll
                    for (int tn = 0; tn < 2; ++tn)
                        crow[tn * 16] = acc[tm][tn][i] + bvs[tn];
                } else {
                    int n   = row / LEN_IN_;
                    int pix = row - n * LEN_IN_;
#pragma unroll
                    for (int tn = 0; tn < 2; ++tn) {
                        int col = col0 + wcol + tn * 16 + r16;
                        int h = col >> 5, dh = col & 31;
                        size_t addr = ((size_t)(n * NH_ + h) * LEN_IN_ + pix) * DH_ + dh;
                        Cb[addr] = f2bf_rne(acc[tm][tn][i] + bvs[tn]);
                    }
                }
            }
        }
    }
}

// ---------------------------------------------------------------------------
// Fused softmax + location + bilinear sampling + weighted accumulation.
// One block per 8 queries. Stage: 256 threads = (q=tid>>5, h=(tid>>2)&7,
// l=tid&3) building 16B descriptors (ushort4 idx + half4 aw-premult weights).
// Gather: 256 threads = (q, h, dhg=tid&3), bf16x8 (16B) corner loads.
// ---------------------------------------------------------------------------
__global__ __launch_bounds__(256) void ms_sample(
    const unsigned short* __restrict__ value,  // (n, 8, len_in, 32) bf16
    const float* __restrict__ comb,            // (n*lq, 768): off(512) | logit(256)
    const float* __restrict__ ref_pts,         // (n*lq, 4, 2)
    float* __restrict__ out)                   // (n*lq, 256)
{
    __shared__ uint4 s_desc[2048];             // [q][h][32]

    const int bid = blockIdx.x;
    const int tid = threadIdx.x;

    { // ---- stage ----
        int q = tid >> 5, h = (tid >> 2) & 7, l = tid & 3;
        int nq = bid * 8 + q;
        const float* row = comb + (size_t)nq * 768;

        float4 L0 = *(const float4*)&row[512 + h * 32 + l * 8];
        float4 L1 = *(const float4*)&row[512 + h * 32 + l * 8 + 4];
        float lg[8] = {L0.x, L0.y, L0.z, L0.w, L1.x, L1.y, L1.z, L1.w};
        float m = lg[0];
#pragma unroll
        for (int i = 1; i < 8; ++i) m = fmaxf(m, lg[i]);
        m = fmaxf(m, __shfl_xor(m, 1));
        m = fmaxf(m, __shfl_xor(m, 2));
        float e[8], s = 0.f;
#pragma unroll
        for (int i = 0; i < 8; ++i) { e[i] = __expf(lg[i] - m); s += e[i]; }
        s += __shfl_xor(s, 1);
        s += __shfl_xor(s, 2);
        float inv = 1.f / s;

        float4 R0 = *(const float4*)&ref_pts[(size_t)nq * 8];
        float4 R1 = *(const float4*)&ref_pts[(size_t)nq * 8 + 4];
        float rx[4] = {R0.x, R0.z, R1.x, R1.z};
        float ry[4] = {R0.y, R0.w, R1.y, R1.w};

        float off[16];
#pragma unroll
        for (int i = 0; i < 4; ++i)
            *(float4*)&off[i * 4] = *(const float4*)&row[h * 64 + l * 16 + i * 4];

        float wl = (float)c_w[l], hl = (float)c_h[l];
        int wli = c_w[l], hli = c_h[l], st = c_start[l];
        uint4* dst = &s_desc[((q * 8 + h) * 4 + l) * 8];
#pragma unroll
        for (int p = 0; p < 8; ++p) {
            int z = p & 3;
            float a = e[p] * inv;
            float x = rx[z] * wl + off[p * 2 + 0] - 0.5f;
            float y = ry[z] * hl + off[p * 2 + 1] - 0.5f;
            float x0f = floorf(x), y0f = floorf(y);
            int   x0 = (int)x0f,  y0 = (int)y0f;
            float wx = x - x0f,   wy = y - y0f;
            unsigned short ix[4];
            float wt[4];
#pragma unroll
            for (int j = 0; j < 4; ++j) {
                int xi = x0 + (j & 1);
                int yi = y0 + (j >> 1);
                float w = ((j & 1) ? wx : 1.f - wx) * ((j >> 1) ? wy : 1.f - wy);
                bool valid = (xi >= 0) && (xi < wli) && (yi >= 0) && (yi < hli);
                int xc = min(max(xi, 0), wli - 1);
                int yc = min(max(yi, 0), hli - 1);
                ix[j] = (unsigned short)(st + yc * wli + xc);
                wt[j] = valid ? a * w : 0.f;
            }
            uint4 d;
            d.x = (unsigned int)ix[0] | ((unsigned int)ix[1] << 16);
            d.y = (unsigned int)ix[2] | ((unsigned int)ix[3] << 16);
            __half2 h01 = __floats2half2_rn(wt[0], wt[1]);
            __half2 h23 = __floats2half2_rn(wt[2], wt[3]);
            d.z = *(unsigned int*)&h01;
            d.w = *(unsigned int*)&h23;
            dst[p] = d;
        }
    }
    __syncthreads();

    // ---- gather ----
    int q = tid >> 5, h = (tid >> 2) & 7, dhg = tid & 3;
    int nq = bid * 8 + q;
    int n  = nq / LQ_;
    const unsigned short* vb = value
        + ((size_t)(n * NH_ + h) * LEN_IN_) * DH_ + dhg * 8;
    const uint4* desc = &s_desc[(q * 8 + h) * 32];

    float acc[8];
#pragma unroll
    for (int i = 0; i < 8; ++i) acc[i] = 0.f;

#pragma unroll 2
    for (int s = 0; s < 32; ++s) {
        uint4 d = desc[s];
        float2 w01 = __half22float2(*(const __half2*)&d.z);
        float2 w23 = __half22float2(*(const __half2*)&d.w);
        int i0 = d.x & 0xFFFF, i1 = d.x >> 16;
        int i2 = d.y & 0xFFFF, i3 = d.y >> 16;
        uint4 v0 = *(const uint4*)(vb + i0 * DH_);
        uint4 v1 = *(const uint4*)(vb + i1 * DH_);
        uint4 v2 = *(const uint4*)(vb + i2 * DH_);
        uint4 v3 = *(const uint4*)(vb + i3 * DH_);
        const uint4* vv[4] = {&v0, &v1, &v2, &v3};
        float ww[4] = {w01.x, w01.y, w23.x, w23.y};
#pragma unroll
        for (int c = 0; c < 4; ++c) {
            uint4 v = *vv[c];
            float w = ww[c];
            acc[0] = fmaf(__uint_as_float(v.x << 16), w, acc[0]);
            acc[1] = fmaf(__uint_as_float(v.x & 0xFFFF0000u), w, acc[1]);
            acc[2] = fmaf(__uint_as_float(v.y << 16), w, acc[2]);
            acc[3] = fmaf(__uint_as_float(v.y & 0xFFFF0000u), w, acc[3]);
            acc[4] = fmaf(__uint_as_float(v.z << 16), w, acc[4]);
            acc[5] = fmaf(__uint_as_float(v.z & 0xFFFF0000u), w, acc[5]);
            acc[6] = fmaf(__uint_as_float(v.w << 16), w, acc[6]);
            acc[7] = fmaf(__uint_as_float(v.w & 0xFFFF0000u), w, acc[7]);
        }
    }

    float* op = out + (size_t)nq * 256 + h * 32 + dhg * 8;
    *(float4*)&op[0] = make_float4(acc[0], acc[1], acc[2], acc[3]);
    *(float4*)&op[4] = make_float4(acc[4], acc[5], acc[6], acc[7]);
}

// ---------------------------------------------------------------------------
extern "C" void kernel_launch(void* const* d_in, const int* in_sizes, int n_in,
                              void* d_out, int out_size, void* d_ws, size_t ws_size,
                              hipStream_t stream)
{
    const float* query         = (const float*)d_in[0];
    const float* ref_pts       = (const float*)d_in[2];
    const float* input_flatten = (const float*)d_in[3];
    const float* Wv            = (const float*)d_in[6];
    const float* bv            = (const float*)d_in[7];
    const float* Wo            = (const float*)d_in[8];
    const float* bo            = (const float*)d_in[9];
    const float* Wa            = (const float*)d_in[10];
    const float* ba            = (const float*)d_in[11];
    float* out = (float*)d_out;

    char* ws = (char*)d_ws;
    size_t o = 0;
    unsigned short* Wv_hi = (unsigned short*)(ws + o); o += 256 * 256 * 2;
    unsigned short* Wv_lo = (unsigned short*)(ws + o); o += 256 * 256 * 2;
    unsigned short* Wc_hi = (unsigned short*)(ws + o); o += 768 * 256 * 2;
    unsigned short* Wc_lo = (unsigned short*)(ws + o); o += 768 * 256 * 2;
    float*          bcomb = (float*)(ws + o);          o += 768 * 4;
    o = (o + 511) & ~(size_t)511;
    unsigned short* value = (unsigned short*)(ws + o); o += (size_t)119680 * 256 * 2;
    o = (o + 511) & ~(size_t)511;
    float* combq = (float*)(ws + o); o += (size_t)20000 * 768 * 4;

    const int MV = N_BATCH * LEN_IN_;  // 119680
    const int MQ = N_BATCH * LQ_;      // 20000

    hipLaunchKernelGGL(conv_weights, dim3(1024), dim3(256), 0, stream,
                       Wv, Wo, Wa, bo, ba, Wv_hi, Wv_lo, Wc_hi, Wc_lo, bcomb);
    // value (bf16, (n,h,pix,dh) layout) = input_flatten @ Wv + bv
    hipLaunchKernelGGL((gemm_mfma2<true>), dim3((MV / 128) * 2), dim3(512), 0, stream,
                       input_flatten, Wv_hi, Wv_lo, bv, (float*)nullptr, value, MV, 256);
    // [off | logits] = query @ [Wo | Wa] + [bo | ba]   (f32)
    hipLaunchKernelGGL((gemm_mfma2<false>), dim3(((MQ + 127) / 128) * 6), dim3(512), 0, stream,
                       query, Wc_hi, Wc_lo, bcomb, combq, (unsigned short*)nullptr, MQ, 768);
    // fused softmax + loc + bilinear sample + weighted sum
    hipLaunchKernelGGL(ms_sample, dim3(MQ / 8), dim3(256), 0, stream,
                       value, combq, ref_pts, out);
}

// Round 5
// 368.444 us; speedup vs baseline: 1.9072x; 1.0926x over previous
//
#include <hip/hip_runtime.h>
#include <hip/hip_fp16.h>

#define N_BATCH 8
#define LQ_     2500
#define DM_     256
#define NH_     8
#define NL_     4
#define NP_     8
#define DH_     32
#define LEN_IN_ 14960
#define KDIM    256

// Fixed level geometry (matches SPATIAL in the reference)
__constant__ int c_w[4]     = {176, 88, 44, 22};
__constant__ int c_h[4]     = {64, 32, 16, 8};
__constant__ int c_start[4] = {0, 11264, 14080, 14784};

using bf16x8 = __attribute__((ext_vector_type(8))) short;
using f32x4  = __attribute__((ext_vector_type(4))) float;

// Truncation-based split: v ~= hi + lo with |dropped| <= 2^-16 |v|.
static __device__ inline void split_bf16(float v, unsigned short& hi, unsigned short& lo) {
    unsigned int u = __float_as_uint(v);
    hi = (unsigned short)(u >> 16);
    float hif = __uint_as_float(u & 0xFFFF0000u);
    float l = v - hif;
    lo = (unsigned short)(__float_as_uint(l) >> 16);
}

// round-to-nearest-even f32 -> bf16
static __device__ inline unsigned short f2bf_rne(float v) {
    unsigned int u = __float_as_uint(v);
    u += 0x7FFFu + ((u >> 16) & 1u);
    return (unsigned short)(u >> 16);
}

// ---------------------------------------------------------------------------
// One-shot weight preprocessing: transpose to [N][K] (k-contiguous) and split
// into bf16 hi/lo pairs. Wo (256x512) and Wa (256x256) concatenated -> 768 cols.
// ---------------------------------------------------------------------------
__global__ __launch_bounds__(256) void conv_weights(
    const float* __restrict__ Wv, const float* __restrict__ Wo,
    const float* __restrict__ Wa, const float* __restrict__ bo,
    const float* __restrict__ ba,
    unsigned short* __restrict__ Wv_hi, unsigned short* __restrict__ Wv_lo,
    unsigned short* __restrict__ Wc_hi, unsigned short* __restrict__ Wc_lo,
    float* __restrict__ bcomb)
{
    int id = blockIdx.x * 256 + threadIdx.x;
    if (id < 256 * 256) {                       // Wv -> Wv_t[n][k]
        int n = id >> 8, k = id & 255;
        unsigned short h, l;
        split_bf16(Wv[k * 256 + n], h, l);
        Wv_hi[id] = h; Wv_lo[id] = l;
    } else {                                    // [Wo | Wa] -> Wc_t[n][k]
        int id2 = id - 65536;
        if (id2 < 768 * 256) {
            int n = id2 >> 8, k = id2 & 255;
            float v = (n < 512) ? Wo[k * 512 + n] : Wa[k * 256 + (n - 512)];
            unsigned short h, l;
            split_bf16(v, h, l);
            Wc_hi[id2] = h; Wc_lo[id2] = l;
        }
    }
    if (id < 768) bcomb[id] = (id < 512) ? bo[id] : ba[id - 512];
}

// ---------------------------------------------------------------------------
// 2-term split MFMA GEMM: C = A @ B + bias, A RNE-rounded to single bf16
// in-kernel, B pre-split hi/lo (C = Ah*Bh + Ah*Bl; error ~= 2^-9 * rowNorm).
// Block = 512 threads (8 waves), tile 128x128, BK=32; wave owns 64x32.
// Register-prefetch pipeline overlaps next tile's global loads with MFMA.
// XSWIZ=true: XCD-aware block mapping — all column-tiles of a row-panel land
// on one XCD so the A panel is fetched once per XCD (needs nbm = row panels).
// BF16_OUT=true scatters bf16 C into value layout (n, head, pixel, dh).
// ---------------------------------------------------------------------------
template <bool BF16_OUT, bool XSWIZ>
__global__ __launch_bounds__(512, 4) void gemm_mfma2(
    const float* __restrict__ A,
    const unsigned short* __restrict__ Bt_hi,
    const unsigned short* __restrict__ Bt_lo,
    const float* __restrict__ bias,
    float* __restrict__ C,
    unsigned short* __restrict__ Cb,
    int M, int N, int nbm)
{
    __shared__ unsigned short As[128][40];
    __shared__ unsigned short Bh[128][40];
    __shared__ unsigned short Bl[128][40];

    const int tid  = threadIdx.x;
    const int ntn  = N >> 7;
    int by, bx;
    if (XSWIZ) {
        int xcd = blockIdx.x & 7, j = blockIdx.x >> 3;
        by = xcd + 8 * (j / ntn);
        bx = j % ntn;
        if (by >= nbm) return;
    } else {
        by = blockIdx.x / ntn;
        bx = blockIdx.x % ntn;
    }
    const int row0 = by << 7, col0 = bx << 7;
    const int lane = tid & 63, wave = tid >> 6;
    const int wrow = (wave & 1) << 6, wcol = (wave >> 1) << 5;
    const int r16  = lane & 15, quad = lane >> 4;

    // staging indices
    const int ar0 = tid >> 3;            // A row (i-stride 64): 0..63
    const int ac4 = (tid & 7) << 2;      // A k-offset (float4 group)
    const int bn  = tid >> 2;            // B row (col): 0..127
    const int bg  = (tid & 3) << 3;      // B k-offset (uint4 group)

    float4 pa[2];
    uint4  pbh, pbl;

    // prologue: issue loads for kt=0
#pragma unroll
    for (int i = 0; i < 2; ++i) {
        int row = row0 + ar0 + (i << 6);
        pa[i] = (row < M) ? *(const float4*)&A[(size_t)row * KDIM + ac4]
                          : make_float4(0.f, 0.f, 0.f, 0.f);
    }
    {
        size_t goff = (size_t)(col0 + bn) * KDIM + bg;
        pbh = *(const uint4*)&Bt_hi[goff];
        pbl = *(const uint4*)&Bt_lo[goff];
    }

    f32x4 acc[4][2];
#pragma unroll
    for (int i = 0; i < 4; ++i)
#pragma unroll
        for (int j = 0; j < 2; ++j) acc[i][j] = (f32x4){0.f, 0.f, 0.f, 0.f};

#pragma unroll
    for (int kt = 0; kt < KDIM; kt += 32) {
        // ---- store prefetched tile to LDS ----
#pragma unroll
        for (int i = 0; i < 2; ++i) {
            int r = ar0 + (i << 6);
            ushort4 hv;
            hv.x = f2bf_rne(pa[i].x);
            hv.y = f2bf_rne(pa[i].y);
            hv.z = f2bf_rne(pa[i].z);
            hv.w = f2bf_rne(pa[i].w);
            *(ushort4*)&As[r][ac4] = hv;
        }
        *(uint4*)&Bh[bn][bg] = pbh;
        *(uint4*)&Bl[bn][bg] = pbl;
        __syncthreads();

        // ---- issue next tile's loads (overlap with fragments + MFMA) ----
        if (kt + 32 < KDIM) {
#pragma unroll
            for (int i = 0; i < 2; ++i) {
                int row = row0 + ar0 + (i << 6);
                pa[i] = (row < M)
                    ? *(const float4*)&A[(size_t)row * KDIM + kt + 32 + ac4]
                    : make_float4(0.f, 0.f, 0.f, 0.f);
            }
            size_t goff = (size_t)(col0 + bn) * KDIM + kt + 32 + bg;
            pbh = *(const uint4*)&Bt_hi[goff];
            pbl = *(const uint4*)&Bt_lo[goff];
        }

        // ---- fragments + MFMA ----
        bf16x8 fbh[2], fbl[2], fa[4];
#pragma unroll
        for (int tn = 0; tn < 2; ++tn) {
            int n = wcol + tn * 16 + r16;
            fbh[tn] = *(const bf16x8*)&Bh[n][quad << 3];
            fbl[tn] = *(const bf16x8*)&Bl[n][quad << 3];
        }
#pragma unroll
        for (int tm = 0; tm < 4; ++tm)
            fa[tm] = *(const bf16x8*)&As[wrow + tm * 16 + r16][quad << 3];
#pragma unroll
        for (int tm = 0; tm < 4; ++tm)
#pragma unroll
            for (int tn = 0; tn < 2; ++tn) {
                acc[tm][tn] = __builtin_amdgcn_mfma_f32_16x16x32_bf16(fa[tm], fbl[tn], acc[tm][tn], 0, 0, 0);
                acc[tm][tn] = __builtin_amdgcn_mfma_f32_16x16x32_bf16(fa[tm], fbh[tn], acc[tm][tn], 0, 0, 0);
            }
        __syncthreads();
    }

    // ---- epilogue: C/D layout col=lane&15, row=quad*4+reg ----
    float bvs[2];
#pragma unroll
    for (int tn = 0; tn < 2; ++tn) bvs[tn] = bias[col0 + wcol + tn * 16 + r16];
#pragma unroll
    for (int tm = 0; tm < 4; ++tm) {
#pragma unroll
        for (int i = 0; i < 4; ++i) {
            int row = row0 + wrow + tm * 16 + (quad << 2) + i;
            if (row < M) {
                if (!BF16_OUT) {
                    float* crow = C + (size_t)row * N + col0 + wcol + r16;
#pragma unroll
                    for (int tn = 0; tn < 2; ++tn)
                        crow[tn * 16] = acc[tm][tn][i] + bvs[tn];
                } else {
                    int n   = row / LEN_IN_;
                    int pix = row - n * LEN_IN_;
#pragma unroll
                    for (int tn = 0; tn < 2; ++tn) {
                        int col = col0 + wcol + tn * 16 + r16;
                        int h = col >> 5, dh = col & 31;
                        size_t addr = ((size_t)(n * NH_ + h) * LEN_IN_ + pix) * DH_ + dh;
                        Cb[addr] = f2bf_rne(acc[tm][tn][i] + bvs[tn]);
                    }
                }
            }
        }
    }
}

// ---------------------------------------------------------------------------
// Fused softmax + loc + bilinear sampling, XCD-locality version.
// Block = one (n, head) value slice (957 KB) x 64 queries; blockIdx swizzled
// so all blocks of a slice run on one XCD -> slice lives in that XCD's L2.
//   grid = 2560: xcd = b&7, j = b>>3, slice = (j/40)*8 + xcd, chunk = j%40.
// Stage: 256 thr = (q_local, l) -> 16B descriptors (ushort4 idx + half4 w).
// Gather: 256 thr = (q_local, dhg) -> bf16x8 corner loads from one slice.
// Descriptor rows padded to 33 uint4 -> 2-way max bank aliasing (free).
// ---------------------------------------------------------------------------
__global__ __launch_bounds__(256) void ms_sample(
    const unsigned short* __restrict__ value,  // (n, 8, len_in, 32) bf16
    const float* __restrict__ comb,            // (n*lq, 768): off(512) | logit(256)
    const float* __restrict__ ref_pts,         // (n*lq, 4, 2)
    float* __restrict__ out)                   // (n*lq, 256)
{
    __shared__ uint4 s_desc[64][33];

    const int b     = blockIdx.x;
    const int xcd   = b & 7;
    const int j     = b >> 3;
    const int slice = (j / 40) * 8 + xcd;      // 0..63
    const int chunk = j % 40;
    const int n     = slice >> 3, h = slice & 7;
    const int q0    = chunk * 64;
    const int tid   = threadIdx.x;

    { // ---- stage ----
        int ql = tid >> 2, l = tid & 3;
        int q  = q0 + ql;
        if (q < LQ_) {
            int nq = n * LQ_ + q;
            const float* row = comb + (size_t)nq * 768;

            float4 L0 = *(const float4*)&row[512 + h * 32 + l * 8];
            float4 L1 = *(const float4*)&row[512 + h * 32 + l * 8 + 4];
            float lg[8] = {L0.x, L0.y, L0.z, L0.w, L1.x, L1.y, L1.z, L1.w};
            float m = lg[0];
#pragma unroll
            for (int i = 1; i < 8; ++i) m = fmaxf(m, lg[i]);
            m = fmaxf(m, __shfl_xor(m, 1));
            m = fmaxf(m, __shfl_xor(m, 2));
            float e[8], s = 0.f;
#pragma unroll
            for (int i = 0; i < 8; ++i) { e[i] = __expf(lg[i] - m); s += e[i]; }
            s += __shfl_xor(s, 1);
            s += __shfl_xor(s, 2);
            float inv = 1.f / s;

            float4 R0 = *(const float4*)&ref_pts[(size_t)nq * 8];
            float4 R1 = *(const float4*)&ref_pts[(size_t)nq * 8 + 4];
            float rx[4] = {R0.x, R0.z, R1.x, R1.z};
            float ry[4] = {R0.y, R0.w, R1.y, R1.w};

            float off[16];
#pragma unroll
            for (int i = 0; i < 4; ++i)
                *(float4*)&off[i * 4] = *(const float4*)&row[h * 64 + l * 16 + i * 4];

            float wl = (float)c_w[l], hl = (float)c_h[l];
            int wli = c_w[l], hli = c_h[l], st = c_start[l];
#pragma unroll
            for (int p = 0; p < 8; ++p) {
                int z = p & 3;
                float a = e[p] * inv;
                float x = rx[z] * wl + off[p * 2 + 0] - 0.5f;
                float y = ry[z] * hl + off[p * 2 + 1] - 0.5f;
                float x0f = floorf(x), y0f = floorf(y);
                int   x0 = (int)x0f,  y0 = (int)y0f;
                float wx = x - x0f,   wy = y - y0f;
                unsigned short ix[4];
                float wt[4];
#pragma unroll
                for (int jj = 0; jj < 4; ++jj) {
                    int xi = x0 + (jj & 1);
                    int yi = y0 + (jj >> 1);
                    float w = ((jj & 1) ? wx : 1.f - wx) * ((jj >> 1) ? wy : 1.f - wy);
                    bool valid = (xi >= 0) && (xi < wli) && (yi >= 0) && (yi < hli);
                    int xc = min(max(xi, 0), wli - 1);
                    int yc = min(max(yi, 0), hli - 1);
                    ix[jj] = (unsigned short)(yc * wli + xc);
                    wt[jj] = valid ? a * w : 0.f;
                }
                uint4 d;
                d.x = (unsigned int)(st + ix[0]) | ((unsigned int)(st + ix[1]) << 16);
                d.y = (unsigned int)(st + ix[2]) | ((unsigned int)(st + ix[3]) << 16);
                __half2 h01 = __floats2half2_rn(wt[0], wt[1]);
                __half2 h23 = __floats2half2_rn(wt[2], wt[3]);
                d.z = *(unsigned int*)&h01;
                d.w = *(unsigned int*)&h23;
                s_desc[ql][l * 8 + p] = d;
            }
        }
    }
    __syncthreads();

    // ---- gather (value accesses confined to this block's (n,h) slice) ----
    int ql = tid >> 2, dhg = tid & 3;
    int q  = q0 + ql;
    if (q >= LQ_) return;
    int nq = n * LQ_ + q;
    const unsigned short* vb = value
        + ((size_t)(n * NH_ + h) * LEN_IN_) * DH_ + dhg * 8;

    float acc[8];
#pragma unroll
    for (int i = 0; i < 8; ++i) acc[i] = 0.f;

#pragma unroll 2
    for (int s = 0; s < 32; ++s) {
        uint4 d = s_desc[ql][s];
        float2 w01 = __half22float2(*(const __half2*)&d.z);
        float2 w23 = __half22float2(*(const __half2*)&d.w);
        int i0 = d.x & 0xFFFF, i1 = d.x >> 16;
        int i2 = d.y & 0xFFFF, i3 = d.y >> 16;
        uint4 v0 = *(const uint4*)(vb + i0 * DH_);
        uint4 v1 = *(const uint4*)(vb + i1 * DH_);
        uint4 v2 = *(const uint4*)(vb + i2 * DH_);
        uint4 v3 = *(const uint4*)(vb + i3 * DH_);
        const uint4* vv[4] = {&v0, &v1, &v2, &v3};
        float ww[4] = {w01.x, w01.y, w23.x, w23.y};
#pragma unroll
        for (int c = 0; c < 4; ++c) {
            uint4 v = *vv[c];
            float w = ww[c];
            acc[0] = fmaf(__uint_as_float(v.x << 16), w, acc[0]);
            acc[1] = fmaf(__uint_as_float(v.x & 0xFFFF0000u), w, acc[1]);
            acc[2] = fmaf(__uint_as_float(v.y << 16), w, acc[2]);
            acc[3] = fmaf(__uint_as_float(v.y & 0xFFFF0000u), w, acc[3]);
            acc[4] = fmaf(__uint_as_float(v.z << 16), w, acc[4]);
            acc[5] = fmaf(__uint_as_float(v.z & 0xFFFF0000u), w, acc[5]);
            acc[6] = fmaf(__uint_as_float(v.w << 16), w, acc[6]);
            acc[7] = fmaf(__uint_as_float(v.w & 0xFFFF0000u), w, acc[7]);
        }
    }

    float* op = out + (size_t)nq * 256 + h * 32 + dhg * 8;
    *(float4*)&op[0] = make_float4(acc[0], acc[1], acc[2], acc[3]);
    *(float4*)&op[4] = make_float4(acc[4], acc[5], acc[6], acc[7]);
}

// ---------------------------------------------------------------------------
extern "C" void kernel_launch(void* const* d_in, const int* in_sizes, int n_in,
                              void* d_out, int out_size, void* d_ws, size_t ws_size,
                              hipStream_t stream)
{
    const float* query         = (const float*)d_in[0];
    const float* ref_pts       = (const float*)d_in[2];
    const float* input_flatten = (const float*)d_in[3];
    const float* Wv            = (const float*)d_in[6];
    const float* bv            = (const float*)d_in[7];
    const float* Wo            = (const float*)d_in[8];
    const float* bo            = (const float*)d_in[9];
    const float* Wa            = (const float*)d_in[10];
    const float* ba            = (const float*)d_in[11];
    float* out = (float*)d_out;

    char* ws = (char*)d_ws;
    size_t o = 0;
    unsigned short* Wv_hi = (unsigned short*)(ws + o); o += 256 * 256 * 2;
    unsigned short* Wv_lo = (unsigned short*)(ws + o); o += 256 * 256 * 2;
    unsigned short* Wc_hi = (unsigned short*)(ws + o); o += 768 * 256 * 2;
    unsigned short* Wc_lo = (unsigned short*)(ws + o); o += 768 * 256 * 2;
    float*          bcomb = (float*)(ws + o);          o += 768 * 4;
    o = (o + 511) & ~(size_t)511;
    unsigned short* value = (unsigned short*)(ws + o); o += (size_t)119680 * 256 * 2;
    o = (o + 511) & ~(size_t)511;
    float* combq = (float*)(ws + o); o += (size_t)20000 * 768 * 4;

    const int MV = N_BATCH * LEN_IN_;  // 119680
    const int MQ = N_BATCH * LQ_;      // 20000

    hipLaunchKernelGGL(conv_weights, dim3(1024), dim3(256), 0, stream,
                       Wv, Wo, Wa, bo, ba, Wv_hi, Wv_lo, Wc_hi, Wc_lo, bcomb);
    // value (bf16, (n,h,pix,dh) layout) = input_flatten @ Wv + bv
    hipLaunchKernelGGL((gemm_mfma2<true, false>), dim3((MV / 128) * 2), dim3(512), 0, stream,
                       input_flatten, Wv_hi, Wv_lo, bv, (float*)nullptr, value, MV, 256, 0);
    // [off | logits] = query @ [Wo | Wa] + [bo | ba]  (f32), XCD-grouped rows
    // nbm = ceil(20000/128) = 157; grid = 8 xcd * ceil(157/8)=20 * 6 col-tiles
    hipLaunchKernelGGL((gemm_mfma2<false, true>), dim3(8 * 20 * 6), dim3(512), 0, stream,
                       query, Wc_hi, Wc_lo, bcomb, combq, (unsigned short*)nullptr, MQ, 768, 157);
    // fused softmax + loc + bilinear sample + weighted sum (XCD slice-local)
    hipLaunchKernelGGL(ms_sample, dim3(2560), dim3(256), 0, stream,
                       value, combq, ref_pts, out);
}